// Round 7
// baseline (788.549 us; speedup 1.0000x reference)
//
#include <hip/hip_runtime.h>
#include <hip/hip_bf16.h>

typedef __bf16 bf16;
typedef __attribute__((ext_vector_type(4))) __bf16 bf16x4;
typedef __attribute__((ext_vector_type(8))) __bf16 bf16x8;
typedef __attribute__((ext_vector_type(4))) float f32x4;

static __device__ __forceinline__ f32x4 MFMA(bf16x8 a, bf16x8 b, f32x4 c) {
  return __builtin_amdgcn_mfma_f32_16x16x32_bf16(a, b, c, 0, 0, 0);
}

__device__ __forceinline__ float sigm(float x) { return 1.0f / (1.0f + __expf(-x)); }
__device__ __forceinline__ float softplus_(float x) {
  return fmaxf(x, 0.0f) + log1pf(__expf(-fabsf(x)));
}

__device__ __forceinline__ void gl16(const bf16* g, char* l) {
  __builtin_amdgcn_global_load_lds(
      (const __attribute__((address_space(1))) char*)g,
      (__attribute__((address_space(3))) char*)l, 16, 0, 0);
}

// ---------------- fused prep: all f32->bf16 conversions + h0 init ----------------
__global__ void k_prep(const float* __restrict__ whh, const float* __restrict__ wih,
                       const float* __restrict__ act, const float* __restrict__ w1,
                       const float* __restrict__ w2, const float* __restrict__ dw,
                       const float* __restrict__ beliefs, const int* __restrict__ idx_i,
                       bf16* __restrict__ Whd, bf16* __restrict__ Wid,
                       bf16* __restrict__ actd, bf16* __restrict__ w1d,
                       bf16* __restrict__ w2d, bf16* __restrict__ dwd,
                       bf16* __restrict__ hAd) {
  for (int q = blockIdx.x * blockDim.x + threadIdx.x; q < 1994240;
       q += gridDim.x * blockDim.x) {
    const float* src;
    bf16* dst;
    int off;
    if (q < 786432)       { src = whh; dst = Whd;  off = q; }
    else if (q < 835584)  { src = wih; dst = Wid;  off = q - 786432; }
    else if (q < 1359872) { src = act; dst = actd; off = q - 835584; }
    else if (q < 1376256) { src = w1;  dst = w1d;  off = q - 1359872; }
    else if (q < 1392640) { src = w2;  dst = w2d;  off = q - 1376256; }
    else if (q < 1601024) { src = dw;  dst = dwd;  off = q - 1392640; }
    else {
      const int e = (q - 1601024) << 2;
      const int n = e >> 18, rest = e & 262143;
      float4 v = *(const float4*)&beliefs[((size_t)idx_i[n] << 18) + rest];
      bf16x4 o = {(bf16)v.x, (bf16)v.y, (bf16)v.z, (bf16)v.w};
      *(bf16x4*)&hAd[e] = o;
      continue;
    }
    float4 v = *(const float4*)&src[(size_t)off << 2];
    bf16x4 o = {(bf16)v.x, (bf16)v.y, (bf16)v.z, (bf16)v.w};
    *(bf16x4*)&dst[(size_t)off << 2] = o;
  }
}

// ---------------- GRU step v6 ----------------
// Grid 512 = 16 mt(96 rows) x 32 jt(32 j), Rg=2 x Cg=4 XCD layout (as R6).
// Block: 3 waves (192 thr). Wave owns 32 DISTINCT rows (2 m-frags) x 96 gate-cols
// (6 n-frags). A: global->registers direct (no LDS, no cross-wave duplication),
// 2-iter-ahead banked prefetch. B: Wh panel in LDS, triple-buffered, XOR-swizzled
// source, gl16. Per kkI per wave: 6 ds_read_b128 + 12 MFMA.
// vmem batch per iter = 4 gl16 + 4 A-loads = 8 -> counted vmcnt(16/8/0).
__global__ __launch_bounds__(192, 2) void k_gru_step(
    const bf16* __restrict__ hin, bf16* __restrict__ hout,
    const bf16* __restrict__ Wh, const bf16* __restrict__ Wi,
    const bf16* __restrict__ actB,
    const float* __restrict__ b_ih, const float* __restrict__ b_hh,
    const int* __restrict__ idx_i, const int* __restrict__ Kmat,
    bf16* __restrict__ states, int step) {
  const int pid = blockIdx.x;
  const int xcd = pid & 7;
  const int rg = xcd >> 2;        // row-group 0..1
  const int cgp = xcd & 3;        // col-group 0..3
  const int q = pid >> 3;         // 0..63
  const int mtl = q & 7;
  const int jtl = q >> 3;
  const int m0 = rg * 768 + mtl * 96;
  const int j0 = (cgp * 8 + jtl) * 32;

  const int tid = threadIdx.x;
  const int wave = tid / 64, lane = tid & 63;
  const int l15 = lane & 15;
  const int kgrp = lane >> 4;     // 0..3

  __shared__ alignas(16) bf16 Bs[3][96][64];   // 3 x 12 KB (rows = gate*32 + jj)

  // B staging decode: 8 rows per gl16, 4 gl16/wave covers wave*32..+31
  const int srow = lane >> 3;                      // 0..7
  const int scol = (((lane & 7) ^ srow) << 3);     // pre-swizzled source col (elems)

  const bf16* wsrc[4];
  const bf16* wisrc[4];
#pragma unroll
  for (int i = 0; i < 4; ++i) {
    const int prow = wave * 32 + i * 8 + srow;     // 0..95
    const int wr = (prow >> 5) * 1024 + j0 + (prow & 31);
    wsrc[i] = Wh + (size_t)wr * 1024 + scol;
    wisrc[i] = Wi + (size_t)wr * 64 + scol;
  }

  // A: this wave's own rows (disjoint across waves)
  const int arow0 = m0 + wave * 32 + l15;          // mf=0 fragment row
  const bf16* aB0 = hin + (size_t)arow0 * 1024 + kgrp * 8;
  const bf16* aB1 = aB0 + (size_t)16 * 1024;       // mf=1 fragment row
  const int nA0 = arow0 >> 8, nA1 = (arow0 + 16) >> 8;
  const bf16* actA0 =
      actB + ((size_t)(idx_i[nA0] + step) * 256 + (arow0 & 255)) * 64 + kgrp * 8;
  const bf16* actA1 =
      actB + ((size_t)(idx_i[nA1] + step) * 256 + ((arow0 + 16) & 255)) * 64 + kgrp * 8;

  auto stage = [&](int buf, int it) {
    char* dst = (char*)Bs + buf * 12288 + (wave * 32) * 128;
    if (it < 16) {
#pragma unroll
      for (int i = 0; i < 4; ++i) gl16(wsrc[i] + it * 64, dst + i * 1024);
    } else {
#pragma unroll
      for (int i = 0; i < 4; ++i) gl16(wisrc[i], dst + i * 1024);
    }
  };

  bf16x8 areg[3][4];   // [bank][mf*2 + kkI]
  auto loadA = [&](int bank, int it) {
    if (it < 16) {
      areg[bank][0] = *(const bf16x8*)(aB0 + it * 64);
      areg[bank][1] = *(const bf16x8*)(aB0 + it * 64 + 32);
      areg[bank][2] = *(const bf16x8*)(aB1 + it * 64);
      areg[bank][3] = *(const bf16x8*)(aB1 + it * 64 + 32);
    } else {
      areg[bank][0] = *(const bf16x8*)(actA0);
      areg[bank][1] = *(const bf16x8*)(actA0 + 32);
      areg[bank][2] = *(const bf16x8*)(actA1);
      areg[bank][3] = *(const bf16x8*)(actA1 + 32);
    }
  };

  f32x4 accR[2][2], accZ[2][2], accNh[2][2], accNi[2][2];   // [mf][jh]
  const f32x4 zero = {0.f, 0.f, 0.f, 0.f};
#pragma unroll
  for (int a = 0; a < 2; ++a)
#pragma unroll
    for (int b = 0; b < 2; ++b) {
      accR[a][b] = zero; accZ[a][b] = zero; accNh[a][b] = zero; accNi[a][b] = zero;
    }

  // hoisted epilogue constants
  float brc[2], bzc[2], binc[2], bhnc[2];
#pragma unroll
  for (int jh = 0; jh < 2; ++jh) {
    const int j = j0 + jh * 16 + l15;
    brc[jh] = b_ih[j] + b_hh[j];
    bzc[jh] = b_ih[1024 + j] + b_hh[1024 + j];
    binc[jh] = b_ih[2048 + j];
    bhnc[jh] = b_hh[2048 + j];
  }

  auto compute = [&](int slot, f32x4 (&gN)[2][2]) {
    const char* bb = (const char*)Bs + slot * 12288;
#pragma unroll
    for (int kkI = 0; kkI < 2; ++kkI) {
      const int kbyte = (((kkI << 5) + (kgrp << 3)) << 1) ^ ((l15 & 7) << 4);
      bf16x8 br0 = *(const bf16x8*)(bb + (l15) * 128 + kbyte);
      bf16x8 br1 = *(const bf16x8*)(bb + (16 + l15) * 128 + kbyte);
      bf16x8 bz0 = *(const bf16x8*)(bb + (32 + l15) * 128 + kbyte);
      bf16x8 bz1 = *(const bf16x8*)(bb + (48 + l15) * 128 + kbyte);
      bf16x8 bn0 = *(const bf16x8*)(bb + (64 + l15) * 128 + kbyte);
      bf16x8 bn1 = *(const bf16x8*)(bb + (80 + l15) * 128 + kbyte);
#pragma unroll
      for (int mf = 0; mf < 2; ++mf) {
        bf16x8 a = areg[slot][mf * 2 + kkI];
        accR[mf][0] = MFMA(a, br0, accR[mf][0]);
        accR[mf][1] = MFMA(a, br1, accR[mf][1]);
        accZ[mf][0] = MFMA(a, bz0, accZ[mf][0]);
        accZ[mf][1] = MFMA(a, bz1, accZ[mf][1]);
        gN[mf][0] = MFMA(a, bn0, gN[mf][0]);
        gN[mf][1] = MFMA(a, bn1, gN[mf][1]);
      }
    }
  };

  // prologue: batches 0,1 in flight (8 vmem each)
  stage(0, 0); loadA(0, 0);
  stage(1, 1); loadA(1, 1);

#pragma unroll
  for (int t = 0; t < 17; ++t) {
    if (t < 15) { stage((t + 2) % 3, t + 2); loadA((t + 2) % 3, t + 2); }
    if (t <= 14)      asm volatile("s_waitcnt vmcnt(16)" ::: "memory");
    else if (t == 15) asm volatile("s_waitcnt vmcnt(8)" ::: "memory");
    else              asm volatile("s_waitcnt vmcnt(0)" ::: "memory");
    __builtin_amdgcn_s_barrier();
    if (t == 16) compute(1, accNi);          // 16 % 3 == 1
    else         compute(t % 3, accNh);
    __builtin_amdgcn_sched_barrier(0);
    __builtin_amdgcn_s_barrier();
  }

  // ---- epilogue: gates + state update ----
#pragma unroll
  for (int mf = 0; mf < 2; ++mf) {
    const int mbase = m0 + wave * 32 + mf * 16 + kgrp * 4;
    const int n = mbase >> 8;
    const int k0 = Kmat[n * 4 + 0], k1 = Kmat[n * 4 + 1];
    const int k2 = Kmat[n * 4 + 2], k3 = Kmat[n * 4 + 3];
#pragma unroll
    for (int jh = 0; jh < 2; ++jh) {
      const int j = j0 + jh * 16 + l15;
#pragma unroll
      for (int ii = 0; ii < 4; ++ii) {
        const int m = mbase + ii;
        float rgt = sigm(accR[mf][jh][ii] + brc[jh]);
        float zg = sigm(accZ[mf][jh][ii] + bzc[jh]);
        float ng = tanhf(accNi[mf][jh][ii] + binc[jh] + rgt * (accNh[mf][jh][ii] + bhnc[jh]));
        float hp = (float)hin[(size_t)m * 1024 + j];
        float hnew = (1.0f - zg) * ng + zg * hp;
        bf16 hb = (bf16)hnew;
        hout[(size_t)m * 1024 + j] = hb;
        const int b = m & 255;
        if (k0 == step) states[((size_t)(n * 4 + 0) * 256 + b) * 1024 + j] = hb;
        if (k1 == step) states[((size_t)(n * 4 + 1) * 256 + b) * 1024 + j] = hb;
        if (k2 == step) states[((size_t)(n * 4 + 2) * 256 + b) * 1024 + j] = hb;
        if (k3 == step) states[((size_t)(n * 4 + 3) * 256 + b) * 1024 + j] = hb;
      }
    }
  }
}

// ---------------- generic GEMM: C = A(M x K) @ W(N x K)^T, fused epilogues ----------------
template <int EPI, int SWZ>
__global__ __launch_bounds__(256) void k_gemm_epi(
    const bf16* __restrict__ A, const bf16* __restrict__ W, int K, int Nreal, int ld_out,
    const float* __restrict__ bias, const bf16* __restrict__ resid,
    float* __restrict__ outF, bf16* __restrict__ outB) {
  int mt, jt;
  if (SWZ) {
    const int lin = blockIdx.x;
    const int x = lin & 7, k = lin >> 3;
    mt = 12 * x + k % 12;
    jt = k / 12;
  } else {
    mt = blockIdx.x;
    jt = blockIdx.y;
  }
  const int m0 = mt * 64;
  const int j0 = jt * 64;
  const int tid = threadIdx.x, wave = tid >> 6, lane = tid & 63;
  __shared__ alignas(16) bf16 Al[64][72];
  __shared__ alignas(16) bf16 Wl[64][72];

  f32x4 acc[4];
  const f32x4 zero = {0.f, 0.f, 0.f, 0.f};
#pragma unroll
  for (int f = 0; f < 4; ++f) acc[f] = zero;

  const int r = tid >> 3, c8 = (tid & 7) << 3;
  const int arow = wave * 16 + (lane & 15);
  const int koff = (lane >> 4) << 3;

  for (int kb = 0; kb < K; kb += 64) {
    *(bf16x8*)&Al[r][c8]      = *(const bf16x8*)&A[(size_t)(m0 + r) * K + kb + c8];
    *(bf16x8*)&Al[r + 32][c8] = *(const bf16x8*)&A[(size_t)(m0 + r + 32) * K + kb + c8];
    int jr = j0 + r;      if (jr >= Nreal) jr = Nreal - 1;
    int jr2 = j0 + r + 32; if (jr2 >= Nreal) jr2 = Nreal - 1;
    *(bf16x8*)&Wl[r][c8]      = *(const bf16x8*)&W[(size_t)jr * K + kb + c8];
    *(bf16x8*)&Wl[r + 32][c8] = *(const bf16x8*)&W[(size_t)jr2 * K + kb + c8];
    __syncthreads();
#pragma unroll
    for (int kk = 0; kk < 64; kk += 32) {
      bf16x8 av = *(const bf16x8*)&Al[arow][kk + koff];
#pragma unroll
      for (int nf = 0; nf < 4; ++nf) {
        acc[nf] = MFMA(av, *(const bf16x8*)&Wl[nf * 16 + (lane & 15)][kk + koff], acc[nf]);
      }
    }
    __syncthreads();
  }

#pragma unroll
  for (int nf = 0; nf < 4; ++nf) {
    int j = j0 + nf * 16 + (lane & 15);
    float bj = (j < Nreal) ? bias[j] : 0.f;
#pragma unroll
    for (int i = 0; i < 4; ++i) {
      int m = m0 + wave * 16 + ((lane >> 4) << 2) + i;
      float v = acc[nf][i] + bj;
      if (EPI == 0) {
        outB[(size_t)m * ld_out + j] = (bf16)fmaxf(v, 0.f);
      } else if (EPI == 1) {
        v = fmaxf(v, 0.f) + (float)resid[(size_t)m * ld_out + j];
        outB[(size_t)m * ld_out + j] = (bf16)v;
      } else {
        if (j < Nreal) outF[(size_t)m * ld_out + j] = v;
      }
    }
  }
}

// ---------------- loss ----------------
__global__ __launch_bounds__(256) void k_loss_rows(
    const float* __restrict__ logits, const float* __restrict__ obs,
    const int* __restrict__ idx_i, const int* __restrict__ Kmat,
    float* __restrict__ partials) {
  const int row = blockIdx.x;
  const int n = row >> 10, g = (row >> 8) & 3, b = row & 255;
  const int i = idx_i[n], k = Kmat[n * 4 + g];
  const float* L = logits + (size_t)row * 814;
  const float* ob = obs + ((size_t)(k + i + 1) * 256 + b) * 16;
  const int tid = threadIdx.x, lane = tid & 63, wv = tid >> 6;
  __shared__ float red[4];

  float total = 0.f;
#pragma unroll
  for (int p = 0; p < 2; ++p) {
    const float* Lp = L + p * 407;
    const float* tg = ob + p * 8;
    float mx = -1e30f;
    for (int c = tid; c < 400; c += 256) mx = fmaxf(mx, Lp[c]);
#pragma unroll
    for (int s = 32; s; s >>= 1) mx = fmaxf(mx, __shfl_xor(mx, s));
    __syncthreads();
    if (lane == 0) red[wv] = mx;
    __syncthreads();
    mx = fmaxf(fmaxf(red[0], red[1]), fmaxf(red[2], red[3]));
    __syncthreads();
    float se = 0.f;
    for (int c = tid; c < 400; c += 256) se += __expf(Lp[c] - mx);
#pragma unroll
    for (int s = 32; s; s >>= 1) se += __shfl_xor(se, s);
    if (lane == 0) red[wv] = se;
    __syncthreads();
    se = red[0] + red[1] + red[2] + red[3];
    __syncthreads();

    if (tid == 0) {
      int cls = (int)tg[0];
      float lse = mx + logf(se);
      float v = lse - Lp[cls];
      float d0 = Lp[400] - tg[1], d1 = Lp[401] - tg[2];
      v += 0.5f * (d0 * d0 + d1 * d1);
      float s2 = softplus_(Lp[402]) - tg[3]; v += s2 * s2;
      float s3 = softplus_(Lp[403]) - tg[4]; v += s3 * s3;
      v += softplus_(Lp[404]) - Lp[404] * tg[5];
      v += softplus_(Lp[405]) - Lp[405] * tg[6];
      v += softplus_(Lp[406]) - Lp[406] * tg[7];
      total += v;
    }
    __syncthreads();
  }
  if (tid == 0) partials[row] = total * (1.0f / 1024.0f);
}

__global__ void k_reduce_final(const float* __restrict__ partials, float* __restrict__ out) {
  __shared__ float s[256];
  float v = 0.f;
  for (int i = threadIdx.x; i < 6144; i += 256) v += partials[i];
  s[threadIdx.x] = v;
  __syncthreads();
  for (int st = 128; st; st >>= 1) {
    if (threadIdx.x < st) s[threadIdx.x] += s[threadIdx.x + st];
    __syncthreads();
  }
  if (threadIdx.x == 0) out[0] = s[0];
}

// ---------------- launcher ----------------

extern "C" void kernel_launch(void* const* d_in, const int* in_sizes, int n_in,
                              void* d_out, int out_size, void* d_ws, size_t ws_size,
                              hipStream_t stream) {
  const float* obs      = (const float*)d_in[0];
  const float* actions  = (const float*)d_in[1];
  const float* beliefs  = (const float*)d_in[2];
  const float* w_ih     = (const float*)d_in[3];
  const float* w_hh     = (const float*)d_in[4];
  const float* b_ih     = (const float*)d_in[5];
  const float* b_hh     = (const float*)d_in[6];
  const float* pre_w1   = (const float*)d_in[7];
  const float* pre_b1   = (const float*)d_in[8];
  const float* pre_w2   = (const float*)d_in[9];
  const float* pre_b2   = (const float*)d_in[10];
  const float* dec_w    = (const float*)d_in[11];
  const float* dec_b    = (const float*)d_in[12];
  const int*   idx_i    = (const int*)d_in[13];
  const int*   Kmat     = (const int*)d_in[14];
  float* outF = (float*)d_out;

  char* p = (char*)d_ws;
  auto carve = [&](size_t bytes) {
    char* q = p;
    p += (bytes + 255) & ~(size_t)255;
    return q;
  };
  bf16* Wh      = (bf16*)carve(3072u * 1024u * 2u);
  bf16* Wi      = (bf16*)carve(3072u * 64u * 2u);
  bf16* actBv   = (bf16*)carve(128u * 256u * 64u * 2u);
  bf16* preW1b  = (bf16*)carve(64u * 1024u * 2u);
  bf16* preW2b  = (bf16*)carve(1024u * 64u * 2u);
  bf16* decWb   = (bf16*)carve(814u * 1024u * 2u);
  bf16* hA      = (bf16*)carve(1536u * 1024u * 2u);
  bf16* hB      = (bf16*)carve(1536u * 1024u * 2u);
  bf16* states  = (bf16*)carve(6144u * 1024u * 2u);
  bf16* h1      = (bf16*)carve(6144u * 64u * 2u);
  bf16* xbuf    = (bf16*)carve(6144u * 1024u * 2u);
  float* logits = (float*)carve((size_t)6144u * 814u * 4u);
  float* partials = (float*)carve(6144u * 4u);

  k_prep<<<2048, 256, 0, stream>>>(w_hh, w_ih, actions, pre_w1, pre_w2, dec_w,
                                   beliefs, idx_i, Wh, Wi, actBv, preW1b, preW2b,
                                   decWb, hA);

  for (int t = 0; t < 30; ++t) {
    const bf16* hi = (t & 1) ? hB : hA;
    bf16* ho = (t & 1) ? hA : hB;
    k_gru_step<<<512, 192, 0, stream>>>(hi, ho, Wh, Wi, actBv, b_ih, b_hh,
                                        idx_i, Kmat, states, t);
  }

  k_gemm_epi<0, 0><<<dim3(96, 1), 256, 0, stream>>>(states, preW1b, 1024, 64, 64,
                                                    pre_b1, nullptr, nullptr, h1);
  k_gemm_epi<1, 1><<<1536, 256, 0, stream>>>(h1, preW2b, 64, 1024, 1024,
                                             pre_b2, states, nullptr, xbuf);
  k_gemm_epi<2, 1><<<1248, 256, 0, stream>>>(xbuf, decWb, 1024, 814, 814,
                                             dec_b, nullptr, logits, nullptr);

  k_loss_rows<<<6144, 256, 0, stream>>>(logits, obs, idx_i, Kmat, partials);
  k_reduce_final<<<1, 256, 0, stream>>>(partials, outF);
}

// Round 8
// 660.173 us; speedup vs baseline: 1.1945x; 1.1945x over previous
//
#include <hip/hip_runtime.h>
#include <hip/hip_bf16.h>

typedef __bf16 bf16;
typedef __attribute__((ext_vector_type(4))) __bf16 bf16x4;
typedef __attribute__((ext_vector_type(8))) __bf16 bf16x8;
typedef __attribute__((ext_vector_type(4))) float f32x4;

static __device__ __forceinline__ f32x4 MFMA(bf16x8 a, bf16x8 b, f32x4 c) {
  return __builtin_amdgcn_mfma_f32_16x16x32_bf16(a, b, c, 0, 0, 0);
}

__device__ __forceinline__ float sigm(float x) { return 1.0f / (1.0f + __expf(-x)); }
__device__ __forceinline__ float softplus_(float x) {
  return fmaxf(x, 0.0f) + log1pf(__expf(-fabsf(x)));
}

__device__ __forceinline__ void gl16(const bf16* g, char* l) {
  __builtin_amdgcn_global_load_lds(
      (const __attribute__((address_space(1))) char*)g,
      (__attribute__((address_space(3))) char*)l, 16, 0, 0);
}

// ---------------- fused prep: all f32->bf16 conversions + h0 init ----------------
__global__ void k_prep(const float* __restrict__ whh, const float* __restrict__ wih,
                       const float* __restrict__ act, const float* __restrict__ w1,
                       const float* __restrict__ w2, const float* __restrict__ dw,
                       const float* __restrict__ beliefs, const int* __restrict__ idx_i,
                       bf16* __restrict__ Whd, bf16* __restrict__ Wid,
                       bf16* __restrict__ actd, bf16* __restrict__ w1d,
                       bf16* __restrict__ w2d, bf16* __restrict__ dwd,
                       bf16* __restrict__ hAd) {
  for (int q = blockIdx.x * blockDim.x + threadIdx.x; q < 1994240;
       q += gridDim.x * blockDim.x) {
    const float* src;
    bf16* dst;
    int off;
    if (q < 786432)       { src = whh; dst = Whd;  off = q; }
    else if (q < 835584)  { src = wih; dst = Wid;  off = q - 786432; }
    else if (q < 1359872) { src = act; dst = actd; off = q - 835584; }
    else if (q < 1376256) { src = w1;  dst = w1d;  off = q - 1359872; }
    else if (q < 1392640) { src = w2;  dst = w2d;  off = q - 1376256; }
    else if (q < 1601024) { src = dw;  dst = dwd;  off = q - 1392640; }
    else {
      const int e = (q - 1601024) << 2;
      const int n = e >> 18, rest = e & 262143;
      float4 v = *(const float4*)&beliefs[((size_t)idx_i[n] << 18) + rest];
      bf16x4 o = {(bf16)v.x, (bf16)v.y, (bf16)v.z, (bf16)v.w};
      *(bf16x4*)&hAd[e] = o;
      continue;
    }
    float4 v = *(const float4*)&src[(size_t)off << 2];
    bf16x4 o = {(bf16)v.x, (bf16)v.y, (bf16)v.z, (bf16)v.w};
    *(bf16x4*)&dst[(size_t)off << 2] = o;
  }
}

// ---------------- GRU step v7: v5 K-loop (R6, proven) + coalesced LDS-transpose epilogue ----
// Grid 512 = 16 mt(96 rows) x 32 jt(32 j), Rg=2 x Cg=4 XCD layout. Block 256 thr,
// 2 blocks/CU. A+B LDS-staged via gl16, triple-buffered, XOR-swizzled source,
// counted vmcnt. Epilogue: hp tile pre-loaded coalesced (8B/thread x3) at t==14,
// LDS-transpose exchange, gates, coalesced 8B stores for hout/states
// (replaces per-element 2B gather/scatter that cost ~7us/step).
__global__ __launch_bounds__(256, 2) void k_gru_step(
    const bf16* __restrict__ hin, bf16* __restrict__ hout,
    const bf16* __restrict__ Wh, const bf16* __restrict__ Wi,
    const bf16* __restrict__ actB,
    const float* __restrict__ b_ih, const float* __restrict__ b_hh,
    const int* __restrict__ idx_i, const int* __restrict__ Kmat,
    bf16* __restrict__ states, int step) {
  const int pid = blockIdx.x;
  const int xcd = pid & 7;
  const int rg = xcd >> 2;        // row-group 0..1
  const int cgp = xcd & 3;        // col-group 0..3
  const int q = pid >> 3;         // 0..63
  const int mtl = q & 7;
  const int jtl = q >> 3;
  const int m0 = rg * 768 + mtl * 96;
  const int j0 = (cgp * 8 + jtl) * 32;

  const int tid = threadIdx.x, wave = tid >> 6, lane = tid & 63;
  const int l15 = lane & 15;
  const int kgrp = lane >> 4;     // 0..3
  const int wm = wave >> 1;       // 0..1 : row half (48)
  const int wj = wave & 1;        // 0..1 : j half (16)
  const int jlane = j0 + wj * 16 + l15;

  __shared__ alignas(16) bf16 As[3][96][64];   // 3 x 12 KB
  __shared__ alignas(16) bf16 Bs[3][96][64];   // 3 x 12 KB  (rows = g*32 + jj)

  const int srow = lane >> 3;                      // 0..7
  const int scol = (((lane & 7) ^ srow) << 3);     // pre-swizzled source col (elems)

  const bf16* asrc[3];
  const bf16* bsrc[3];
  const bf16* aisrc[3];
  const bf16* bisrc[3];
#pragma unroll
  for (int i = 0; i < 3; ++i) {
    const int prow = wave * 24 + i * 8 + srow;     // 0..95
    const int grow = m0 + prow;
    asrc[i] = hin + (size_t)grow * 1024 + scol;
    const int wr = (prow >> 5) * 1024 + j0 + (prow & 31);
    bsrc[i] = Wh + (size_t)wr * 1024 + scol;
    bisrc[i] = Wi + (size_t)wr * 64 + scol;
    const int np = grow >> 8;
    aisrc[i] = actB + ((size_t)(idx_i[np] + step) * 256 + (grow & 255)) * 64 + scol;
  }

  auto stage = [&](int buf, int it) {
    char* ad = (char*)As + buf * 12288 + (wave * 24) * 128;
    char* bd = (char*)Bs + buf * 12288 + (wave * 24) * 128;
    if (it < 16) {
#pragma unroll
      for (int i = 0; i < 3; ++i) {
        gl16(asrc[i] + it * 64, ad + i * 1024);
        gl16(bsrc[i] + it * 64, bd + i * 1024);
      }
    } else {
#pragma unroll
      for (int i = 0; i < 3; ++i) {
        gl16(aisrc[i], ad + i * 1024);
        gl16(bisrc[i], bd + i * 1024);
      }
    }
  };

  f32x4 accR[3], accZ[3], accNh[3], accNi[3];
  const f32x4 zero = {0.f, 0.f, 0.f, 0.f};
#pragma unroll
  for (int f = 0; f < 3; ++f) { accR[f] = zero; accZ[f] = zero; accNh[f] = zero; accNi[f] = zero; }

  const float br = b_ih[jlane] + b_hh[jlane];
  const float bz = b_ih[1024 + jlane] + b_hh[1024 + jlane];
  const float bin = b_ih[2048 + jlane];
  const float bhn = b_hh[2048 + jlane];

  auto compute = [&](int buf, f32x4 (&gN)[3]) {
    const char* ab = (const char*)As + buf * 12288;
    const char* bb = (const char*)Bs + buf * 12288;
#pragma unroll
    for (int kkI = 0; kkI < 2; ++kkI) {
      const int kbyte = (((kkI << 5) + (kgrp << 3)) << 1) ^ ((l15 & 7) << 4);
      bf16x8 a0 = *(const bf16x8*)(ab + (wm * 48 + l15) * 128 + kbyte);
      bf16x8 a1 = *(const bf16x8*)(ab + (wm * 48 + 16 + l15) * 128 + kbyte);
      bf16x8 a2 = *(const bf16x8*)(ab + (wm * 48 + 32 + l15) * 128 + kbyte);
      bf16x8 b_r = *(const bf16x8*)(bb + (wj * 16 + l15) * 128 + kbyte);
      bf16x8 b_z = *(const bf16x8*)(bb + (32 + wj * 16 + l15) * 128 + kbyte);
      bf16x8 b_n = *(const bf16x8*)(bb + (64 + wj * 16 + l15) * 128 + kbyte);
      accR[0] = MFMA(a0, b_r, accR[0]);
      accR[1] = MFMA(a1, b_r, accR[1]);
      accR[2] = MFMA(a2, b_r, accR[2]);
      accZ[0] = MFMA(a0, b_z, accZ[0]);
      accZ[1] = MFMA(a1, b_z, accZ[1]);
      accZ[2] = MFMA(a2, b_z, accZ[2]);
      gN[0] = MFMA(a0, b_n, gN[0]);
      gN[1] = MFMA(a1, b_n, gN[1]);
      gN[2] = MFMA(a2, b_n, gN[2]);
    }
  };

  stage(0, 0);
  stage(1, 1);

  uint2 hpreg[3];

#pragma unroll
  for (int t = 0; t < 17; ++t) {
    if (t < 15) stage((t + 2) % 3, t + 2);
    if (t == 14) {
      // coalesced hp prefetch: 96 rows x 64B of hin[m0..][j0..j0+31]
#pragma unroll
      for (int it2 = 0; it2 < 3; ++it2) {
        const int u = it2 * 256 + tid;
        const int row = u >> 3, c = u & 7;
        hpreg[it2] = *(const uint2*)(hin + (size_t)(m0 + row) * 1024 + j0 + c * 4);
      }
    }
    if (t <= 13)      asm volatile("s_waitcnt vmcnt(12)" ::: "memory");
    else if (t == 14) asm volatile("s_waitcnt vmcnt(15)" ::: "memory");
    else if (t == 15) asm volatile("s_waitcnt vmcnt(9)" ::: "memory");
    else              asm volatile("s_waitcnt vmcnt(0)" ::: "memory");
    __builtin_amdgcn_s_barrier();
    if (t == 16) compute(1, accNi);          // 16 % 3 == 1
    else         compute(t % 3, accNh);
    __builtin_amdgcn_sched_barrier(0);
    __builtin_amdgcn_s_barrier();
  }

  // ---- epilogue: LDS-transpose exchange, coalesced stores ----
  // Hp reuses As slot 0 (dead); Hn reuses Bs slot 0 (dead). Stride 40 bf16 (80B).
  bf16* Hp = (bf16*)&As[0][0][0];
  bf16* Hn = (bf16*)&Bs[0][0][0];

#pragma unroll
  for (int it2 = 0; it2 < 3; ++it2) {
    const int u = it2 * 256 + tid;
    const int row = u >> 3, c = u & 7;
    *(uint2*)&Hp[row * 40 + c * 4] = hpreg[it2];
  }
  __syncthreads();

#pragma unroll
  for (int mf = 0; mf < 3; ++mf) {
#pragma unroll
    for (int ii = 0; ii < 4; ++ii) {
      const int ml = wm * 48 + mf * 16 + kgrp * 4 + ii;
      const int jl = wj * 16 + l15;
      float hp = (float)Hp[ml * 40 + jl];
      float rg2 = sigm(accR[mf][ii] + br);
      float zg = sigm(accZ[mf][ii] + bz);
      float ng = tanhf(accNi[mf][ii] + bin + rg2 * (accNh[mf][ii] + bhn));
      float hnew = (1.0f - zg) * ng + zg * hp;
      Hn[ml * 40 + jl] = (bf16)hnew;
    }
  }
  __syncthreads();

#pragma unroll
  for (int it2 = 0; it2 < 3; ++it2) {
    const int u = it2 * 256 + tid;
    const int row = u >> 3, c = u & 7;
    const int m = m0 + row;
    uint2 v = *(const uint2*)&Hn[row * 40 + c * 4];
    *(uint2*)&hout[(size_t)m * 1024 + j0 + c * 4] = v;
    const int n = m >> 8;
    const int b = m & 255;
#pragma unroll
    for (int g = 0; g < 4; ++g) {
      if (Kmat[n * 4 + g] == step)
        *(uint2*)&states[((size_t)(n * 4 + g) * 256 + b) * 1024 + j0 + c * 4] = v;
    }
  }
}

// ---------------- generic GEMM: C = A(M x K) @ W(N x K)^T, fused epilogues ----------------
template <int EPI, int SWZ>
__global__ __launch_bounds__(256) void k_gemm_epi(
    const bf16* __restrict__ A, const bf16* __restrict__ W, int K, int Nreal, int ld_out,
    const float* __restrict__ bias, const bf16* __restrict__ resid,
    float* __restrict__ outF, bf16* __restrict__ outB) {
  int mt, jt;
  if (SWZ) {
    const int lin = blockIdx.x;
    const int x = lin & 7, k = lin >> 3;
    mt = 12 * x + k % 12;
    jt = k / 12;
  } else {
    mt = blockIdx.x;
    jt = blockIdx.y;
  }
  const int m0 = mt * 64;
  const int j0 = jt * 64;
  const int tid = threadIdx.x, wave = tid >> 6, lane = tid & 63;
  __shared__ alignas(16) bf16 Al[64][72];
  __shared__ alignas(16) bf16 Wl[64][72];

  f32x4 acc[4];
  const f32x4 zero = {0.f, 0.f, 0.f, 0.f};
#pragma unroll
  for (int f = 0; f < 4; ++f) acc[f] = zero;

  const int r = tid >> 3, c8 = (tid & 7) << 3;
  const int arow = wave * 16 + (lane & 15);
  const int koff = (lane >> 4) << 3;

  for (int kb = 0; kb < K; kb += 64) {
    *(bf16x8*)&Al[r][c8]      = *(const bf16x8*)&A[(size_t)(m0 + r) * K + kb + c8];
    *(bf16x8*)&Al[r + 32][c8] = *(const bf16x8*)&A[(size_t)(m0 + r + 32) * K + kb + c8];
    int jr = j0 + r;      if (jr >= Nreal) jr = Nreal - 1;
    int jr2 = j0 + r + 32; if (jr2 >= Nreal) jr2 = Nreal - 1;
    *(bf16x8*)&Wl[r][c8]      = *(const bf16x8*)&W[(size_t)jr * K + kb + c8];
    *(bf16x8*)&Wl[r + 32][c8] = *(const bf16x8*)&W[(size_t)jr2 * K + kb + c8];
    __syncthreads();
#pragma unroll
    for (int kk = 0; kk < 64; kk += 32) {
      bf16x8 av = *(const bf16x8*)&Al[arow][kk + koff];
#pragma unroll
      for (int nf = 0; nf < 4; ++nf) {
        acc[nf] = MFMA(av, *(const bf16x8*)&Wl[nf * 16 + (lane & 15)][kk + koff], acc[nf]);
      }
    }
    __syncthreads();
  }

#pragma unroll
  for (int nf = 0; nf < 4; ++nf) {
    int j = j0 + nf * 16 + (lane & 15);
    float bj = (j < Nreal) ? bias[j] : 0.f;
#pragma unroll
    for (int i = 0; i < 4; ++i) {
      int m = m0 + wave * 16 + ((lane >> 4) << 2) + i;
      float v = acc[nf][i] + bj;
      if (EPI == 0) {
        outB[(size_t)m * ld_out + j] = (bf16)fmaxf(v, 0.f);
      } else if (EPI == 1) {
        v = fmaxf(v, 0.f) + (float)resid[(size_t)m * ld_out + j];
        outB[(size_t)m * ld_out + j] = (bf16)v;
      } else {
        if (j < Nreal) outF[(size_t)m * ld_out + j] = v;
      }
    }
  }
}

// ---------------- loss ----------------
__global__ __launch_bounds__(256) void k_loss_rows(
    const float* __restrict__ logits, const float* __restrict__ obs,
    const int* __restrict__ idx_i, const int* __restrict__ Kmat,
    float* __restrict__ partials) {
  const int row = blockIdx.x;
  const int n = row >> 10, g = (row >> 8) & 3, b = row & 255;
  const int i = idx_i[n], k = Kmat[n * 4 + g];
  const float* L = logits + (size_t)row * 814;
  const float* ob = obs + ((size_t)(k + i + 1) * 256 + b) * 16;
  const int tid = threadIdx.x, lane = tid & 63, wv = tid >> 6;
  __shared__ float red[4];

  float total = 0.f;
#pragma unroll
  for (int p = 0; p < 2; ++p) {
    const float* Lp = L + p * 407;
    const float* tg = ob + p * 8;
    float mx = -1e30f;
    for (int c = tid; c < 400; c += 256) mx = fmaxf(mx, Lp[c]);
#pragma unroll
    for (int s = 32; s; s >>= 1) mx = fmaxf(mx, __shfl_xor(mx, s));
    __syncthreads();
    if (lane == 0) red[wv] = mx;
    __syncthreads();
    mx = fmaxf(fmaxf(red[0], red[1]), fmaxf(red[2], red[3]));
    __syncthreads();
    float se = 0.f;
    for (int c = tid; c < 400; c += 256) se += __expf(Lp[c] - mx);
#pragma unroll
    for (int s = 32; s; s >>= 1) se += __shfl_xor(se, s);
    if (lane == 0) red[wv] = se;
    __syncthreads();
    se = red[0] + red[1] + red[2] + red[3];
    __syncthreads();

    if (tid == 0) {
      int cls = (int)tg[0];
      float lse = mx + logf(se);
      float v = lse - Lp[cls];
      float d0 = Lp[400] - tg[1], d1 = Lp[401] - tg[2];
      v += 0.5f * (d0 * d0 + d1 * d1);
      float s2 = softplus_(Lp[402]) - tg[3]; v += s2 * s2;
      float s3 = softplus_(Lp[403]) - tg[4]; v += s3 * s3;
      v += softplus_(Lp[404]) - Lp[404] * tg[5];
      v += softplus_(Lp[405]) - Lp[405] * tg[6];
      v += softplus_(Lp[406]) - Lp[406] * tg[7];
      total += v;
    }
    __syncthreads();
  }
  if (tid == 0) partials[row] = total * (1.0f / 1024.0f);
}

__global__ void k_reduce_final(const float* __restrict__ partials, float* __restrict__ out) {
  __shared__ float s[256];
  float v = 0.f;
  for (int i = threadIdx.x; i < 6144; i += 256) v += partials[i];
  s[threadIdx.x] = v;
  __syncthreads();
  for (int st = 128; st; st >>= 1) {
    if (threadIdx.x < st) s[threadIdx.x] += s[threadIdx.x + st];
    __syncthreads();
  }
  if (threadIdx.x == 0) out[0] = s[0];
}

// ---------------- launcher ----------------

extern "C" void kernel_launch(void* const* d_in, const int* in_sizes, int n_in,
                              void* d_out, int out_size, void* d_ws, size_t ws_size,
                              hipStream_t stream) {
  const float* obs      = (const float*)d_in[0];
  const float* actions  = (const float*)d_in[1];
  const float* beliefs  = (const float*)d_in[2];
  const float* w_ih     = (const float*)d_in[3];
  const float* w_hh     = (const float*)d_in[4];
  const float* b_ih     = (const float*)d_in[5];
  const float* b_hh     = (const float*)d_in[6];
  const float* pre_w1   = (const float*)d_in[7];
  const float* pre_b1   = (const float*)d_in[8];
  const float* pre_w2   = (const float*)d_in[9];
  const float* pre_b2   = (const float*)d_in[10];
  const float* dec_w    = (const float*)d_in[11];
  const float* dec_b    = (const float*)d_in[12];
  const int*   idx_i    = (const int*)d_in[13];
  const int*   Kmat     = (const int*)d_in[14];
  float* outF = (float*)d_out;

  char* p = (char*)d_ws;
  auto carve = [&](size_t bytes) {
    char* q = p;
    p += (bytes + 255) & ~(size_t)255;
    return q;
  };
  bf16* Wh      = (bf16*)carve(3072u * 1024u * 2u);
  bf16* Wi      = (bf16*)carve(3072u * 64u * 2u);
  bf16* actBv   = (bf16*)carve(128u * 256u * 64u * 2u);
  bf16* preW1b  = (bf16*)carve(64u * 1024u * 2u);
  bf16* preW2b  = (bf16*)carve(1024u * 64u * 2u);
  bf16* decWb   = (bf16*)carve(814u * 1024u * 2u);
  bf16* hA      = (bf16*)carve(1536u * 1024u * 2u);
  bf16* hB      = (bf16*)carve(1536u * 1024u * 2u);
  bf16* states  = (bf16*)carve(6144u * 1024u * 2u);
  bf16* h1      = (bf16*)carve(6144u * 64u * 2u);
  bf16* xbuf    = (bf16*)carve(6144u * 1024u * 2u);
  float* logits = (float*)carve((size_t)6144u * 814u * 4u);
  float* partials = (float*)carve(6144u * 4u);

  k_prep<<<2048, 256, 0, stream>>>(w_hh, w_ih, actions, pre_w1, pre_w2, dec_w,
                                   beliefs, idx_i, Wh, Wi, actBv, preW1b, preW2b,
                                   decWb, hA);

  for (int t = 0; t < 30; ++t) {
    const bf16* hi = (t & 1) ? hB : hA;
    bf16* ho = (t & 1) ? hA : hB;
    k_gru_step<<<512, 256, 0, stream>>>(hi, ho, Wh, Wi, actBv, b_ih, b_hh,
                                        idx_i, Kmat, states, t);
  }

  k_gemm_epi<0, 0><<<dim3(96, 1), 256, 0, stream>>>(states, preW1b, 1024, 64, 64,
                                                    pre_b1, nullptr, nullptr, h1);
  k_gemm_epi<1, 1><<<1536, 256, 0, stream>>>(h1, preW2b, 64, 1024, 1024,
                                             pre_b2, states, nullptr, xbuf);
  k_gemm_epi<2, 1><<<1248, 256, 0, stream>>>(xbuf, decWb, 1024, 814, 814,
                                             dec_b, nullptr, logits, nullptr);

  k_loss_rows<<<6144, 256, 0, stream>>>(logits, obs, idx_i, Kmat, partials);
  k_reduce_final<<<1, 256, 0, stream>>>(partials, outF);
}